// Round 9
// baseline (448.070 us; speedup 1.0000x reference)
//
#include <hip/hip_runtime.h>
#include <stdint.h>

#define NN 6144        // nodes
#define NC 576         // padded V columns (517 used)

typedef float f32x4 __attribute__((ext_vector_type(4)));
typedef __bf16 bf16x8v __attribute__((ext_vector_type(8)));

__device__ __forceinline__ unsigned short f2bf(float f) {
  unsigned u = __float_as_uint(f);
  u += 0x7FFFu + ((u >> 16) & 1u);   // RNE
  return (unsigned short)(u >> 16);
}

// f32 -> OCP e4m3fn, RNE, clamp to +-448
__device__ __forceinline__ unsigned char f2e4m3(float f) {
  unsigned u = __float_as_uint(f);
  unsigned sgn = (u >> 24) & 0x80u;
  unsigned au = u & 0x7FFFFFFFu;
  if (au >= 0x43E00000u) return (unsigned char)(sgn | 0x7E);
  if (au < 0x3C800000u) {
    int q = (int)rintf(__uint_as_float(au) * 512.0f);
    return (unsigned char)(sgn | (q >= 8 ? 0x08 : q));
  }
  unsigned r = au + 0x7FFFFu + ((au >> 20) & 1u);
  int e = (int)(r >> 23) - 127;
  unsigned m = (r >> 20) & 7u;
  return (unsigned char)(sgn | ((unsigned)(e + 7) << 3) | m);
}

__device__ __forceinline__ unsigned short pack2(float a, float b) {
  return (unsigned short)f2e4m3(a) | ((unsigned short)f2e4m3(b) << 8);
}

__device__ __forceinline__ void async_load16(const void* g, void* l) {
  __builtin_amdgcn_global_load_lds(
      (__attribute__((address_space(1))) void*)(uintptr_t)g,
      (__attribute__((address_space(3))) void*)(uint32_t)(uintptr_t)l,
      16, 0, 0);
}

// ---------------- p0: all prep ----------------
// blocks 0..15: Wt transpose; 16: Acat+Wbc+T; 17..40: x->bf16; 41..4648: adj->fp8.
__global__ __launch_bounds__(256) void p0(
    const int* __restrict__ adj, const float* __restrict__ x,
    const float* __restrict__ W, const float* __restrict__ Aw,
    const float* __restrict__ Wb,
    unsigned char* __restrict__ A8, unsigned short* __restrict__ xbf,
    unsigned short* __restrict__ Wt, float* __restrict__ Acat,
    float* __restrict__ T)
{
  const int bid = blockIdx.x, t = threadIdx.x;
  if (bid < 16) {          // Wt[c][k] bf16 = W[h][k][d], c = h*64+d
    const int k = bid * 16 + (t >> 4);
    const int c0 = (t & 15) * 16;
    const int h = c0 >> 6, d0 = c0 & 63;
    const float* wsrc = W + h * 16384 + k * 64 + d0;
    unsigned short* wdst = Wt + (size_t)c0 * 256 + k;
#pragma unroll
    for (int j = 0; j < 16; ++j)
      wdst[(size_t)j * 256] = f2bf(wsrc[j]);
    return;
  }
  if (bid == 16) {         // Acat[0|1][c], Wbc[c] (at Acat+512), T zero
    T[t] = 0.f;
    const int h = t >> 6, d = t & 63;
    Acat[t]       = Aw[h * 128 + d];
    Acat[256 + t] = Aw[h * 128 + 64 + d];
    Acat[512 + t] = Wb[t];             // Wb[h][d] flat = col order h*64+d
    return;
  }
  if (bid < 41) {          // xbf row-major bf16 (24 blocks x 64 float4)
    const int tid = (bid - 17) * 256 + t;
    const float4* xp = (const float4*)x;
    uint2* op = (uint2*)xbf;
#pragma unroll 4
    for (int i = 0; i < 64; ++i) {
      const int g = tid + i * 6144;
      float4 v = xp[g];
      uint2 o;
      o.x = (unsigned)f2bf(v.x) | ((unsigned)f2bf(v.y) << 16);
      o.y = (unsigned)f2bf(v.z) | ((unsigned)f2bf(v.w) << 16);
      op[g] = o;
    }
    return;
  }
  // adj pack: 4608 blocks x 256 thr x 8 int4-groups = 9,437,184 exact, lane-contiguous
  const int pb = bid - 41;
  const int4* a4 = (const int4*)adj;
  unsigned* o1 = (unsigned*)A8;
  const int g0 = pb * 2048 + t;
  int4 q[8];
#pragma unroll
  for (int j = 0; j < 8; ++j) q[j] = a4[g0 + j * 256];
#pragma unroll
  for (int j = 0; j < 8; ++j)
    o1[g0 + j * 256] = (unsigned)q[j].x * 0x38u | (unsigned)q[j].y * 0x3800u |
                       (unsigned)q[j].z * 0x380000u | (unsigned)q[j].w * 0x38000000u;
}

// ---------------- k1_mfma: h = x@W + Wb via MFMA; epilogue e_src, e', V8, T ----------------
// 192 blocks x 256 thr = 768 waves; wave = 16-node m-tile x 128-col half (2 whole heads).
__global__ __launch_bounds__(256) void k1_mfma(
    const unsigned short* __restrict__ xbf, const unsigned short* __restrict__ Wt,
    const float* __restrict__ Acat, const float* __restrict__ Ab,
    unsigned char* __restrict__ V8, float* __restrict__ e_src, float* __restrict__ T)
{
  const int t = threadIdx.x;
  const int w = t >> 6, l = t & 63;
  const int v = blockIdx.x * 4 + w;      // 0..767
  const int mt = v >> 1, nh = v & 1;
  const int i0 = mt * 16, c0 = nh * 128;
  const int lm = l & 15, lk = l >> 4;

  f32x4 acc[8];
#pragma unroll
  for (int nt = 0; nt < 8; ++nt) acc[nt] = (f32x4){0.f, 0.f, 0.f, 0.f};

  const unsigned short* ap = xbf + (size_t)(i0 + lm) * 256 + lk * 8;
  const unsigned short* bp = Wt + (size_t)(c0 + lm) * 256 + lk * 8;

  for (int kb = 0; kb < 256; kb += 32) {
    bf16x8v a = *(const bf16x8v*)(ap + kb);
#pragma unroll
    for (int nt = 0; nt < 8; ++nt) {
      bf16x8v b = *(const bf16x8v*)(bp + (size_t)nt * 16 * 256 + kb);
      acc[nt] = __builtin_amdgcn_mfma_f32_16x16x32_bf16(a, b, acc[nt], 0, 0, 0);
    }
  }

  // C/D: col = c0 + nt*16 + lm, node = i0 + lk*4 + rr.  Add Wb bias.
  float asv[8], adv[8];
#pragma unroll
  for (int nt = 0; nt < 8; ++nt) {
    const int cc = c0 + nt * 16 + lm;
    const float wb = Acat[512 + cc];
#pragma unroll
    for (int rr = 0; rr < 4; ++rr) acc[nt][rr] += wb;
    asv[nt] = Acat[cc];
    adv[nt] = Acat[256 + cc];
  }
#pragma unroll
  for (int nt = 0; nt < 8; ++nt)
    atomicAdd(&T[c0 + nt * 16 + lm], acc[nt][0] + acc[nt][1] + acc[nt][2] + acc[nt][3]);

  float ss[2][4], sd[2][4];
#pragma unroll
  for (int hl = 0; hl < 2; ++hl)
#pragma unroll
    for (int rr = 0; rr < 4; ++rr) {
      float s1 = 0.f, s2 = 0.f;
#pragma unroll
      for (int j = 0; j < 4; ++j) {
        s1 += acc[hl * 4 + j][rr] * asv[hl * 4 + j];
        s2 += acc[hl * 4 + j][rr] * adv[hl * 4 + j];
      }
      ss[hl][rr] = s1; sd[hl][rr] = s2;
    }
#pragma unroll
  for (int off = 1; off < 16; off <<= 1)
#pragma unroll
    for (int hl = 0; hl < 2; ++hl)
#pragma unroll
      for (int rr = 0; rr < 4; ++rr) {
        ss[hl][rr] += __shfl_xor(ss[hl][rr], off);
        sd[hl][rr] += __shfl_xor(sd[hl][rr], off);
      }

  float ed[2][4];
#pragma unroll
  for (int hl = 0; hl < 2; ++hl)
#pragma unroll
    for (int rr = 0; rr < 4; ++rr) ed[hl][rr] = expf(sd[hl][rr]);

  if (lm == 0) {
#pragma unroll
    for (int hl = 0; hl < 2; ++hl) {
      const int hh = nh * 2 + hl;
      const float ab = Ab[hh];
#pragma unroll
      for (int rr = 0; rr < 4; ++rr)
        e_src[(size_t)hh * NN + i0 + lk * 4 + rr] = expf(ss[hl][rr] + ab);
    }
  }

#pragma unroll
  for (int nt = 0; nt < 8; ++nt) {
    const int hl = nt >> 2, hh = nh * 2 + hl;
    const int d = (nt & 3) * 16 + lm;
    unsigned char* pe = V8 + (size_t)(hh * 128 + d) * NN + i0 + lk * 4;
    unsigned char* pp = V8 + (size_t)(hh * 128 + 64 + d) * NN + i0 + lk * 4;
    *(unsigned short*)pe       = pack2(ed[hl][0] * acc[nt][0], ed[hl][1] * acc[nt][1]);
    *(unsigned short*)(pe + 2) = pack2(ed[hl][2] * acc[nt][2], ed[hl][3] * acc[nt][3]);
    *(unsigned short*)pp       = pack2(acc[nt][0], acc[nt][1]);
    *(unsigned short*)(pp + 2) = pack2(acc[nt][2], acc[nt][3]);
  }
  if (lm == 0) {
#pragma unroll
    for (int hl = 0; hl < 2; ++hl) {
      const int hh = nh * 2 + hl;
      unsigned char* pq = V8 + (size_t)(512 + hh) * NN + i0 + lk * 4;
      *(unsigned short*)pq       = pack2(ed[hl][0], ed[hl][1]);
      *(unsigned short*)(pq + 2) = pack2(ed[hl][2], ed[hl][3]);
    }
    if (nh == 0)
      *(unsigned*)(V8 + (size_t)516 * NN + i0 + lk * 4) = 0x38383838u;
  }
}

// ---------------- k2: out2[ks] = A8 @ V8 (R6-verified, unchanged) ----------------
__global__ __launch_bounds__(256, 3) void k2_gemm(
    const unsigned char* __restrict__ A8, const unsigned char* __restrict__ V8,
    float* __restrict__ out2, int nks)
{
  __shared__ unsigned char lB[144 * 64];
  const int t   = threadIdx.x;
  const int bid = blockIdx.x;
  const int cb  = bid & 3;
  const int rb  = (bid >> 2) & 31;
  const int ks  = bid >> 7;
  const int krange = NN / nks;
  const int i0 = rb * 192, n0 = cb * 144, k0 = ks * krange;
  const int w = t >> 6, l = t & 63;
  const int lm = l & 15, lk = l >> 4;

  f32x4 acc[3][9];
#pragma unroll
  for (int mt = 0; mt < 3; ++mt)
#pragma unroll
    for (int nt = 0; nt < 9; ++nt) acc[mt][nt] = (f32x4){0.f, 0.f, 0.f, 0.f};

  const unsigned char* gA0 = A8 + (size_t)(i0 + w * 48 + lm) * NN + k0 + lk * 16;

  const int iters = krange / 64;
  for (int it = 0; it < iters; ++it) {
    const int kb = k0 + it * 64;
    {
      const unsigned char* gB = V8 + (size_t)n0 * NN + kb;
#pragma unroll
      for (int u = 0; u < 2; ++u) {
        const int gi = u * 256 + t;
        const int col = gi >> 2;
        const int g = (gi & 3) ^ ((col ^ (col >> 2)) & 3);
        async_load16(gB + (size_t)col * NN + g * 16,
                     (char*)lB + (size_t)(u * 256 + (t & ~63)) * 16);
      }
      if (t < 64) {
        const int gi = 512 + t;
        const int col = gi >> 2;
        const int g = (gi & 3) ^ ((col ^ (col >> 2)) & 3);
        async_load16(gB + (size_t)col * NN + g * 16, (char*)lB + (size_t)512 * 16);
      }
    }
    longlong2 afr[3];
    const unsigned char* gA = gA0 + it * 64;
#pragma unroll
    for (int mt = 0; mt < 3; ++mt)
      afr[mt] = *(const longlong2*)(gA + (size_t)mt * 16 * NN);
    __syncthreads();
#pragma unroll
    for (int ks2 = 0; ks2 < 2; ++ks2) {
#pragma unroll
      for (int nt = 0; nt < 9; ++nt) {
        const int cc = nt * 16 + lm;
        const int sc = (cc ^ (cc >> 2)) & 3;
        long b = *(const long*)(lB + cc * 64 + ((lk ^ sc) * 16) + ks2 * 8);
#pragma unroll
        for (int mt = 0; mt < 3; ++mt)
          acc[mt][nt] = __builtin_amdgcn_mfma_f32_16x16x32_fp8_fp8(
              ks2 ? afr[mt].y : afr[mt].x, b, acc[mt][nt], 0, 0, 0);
      }
    }
    __syncthreads();
  }

  float* o = out2 + (size_t)ks * ((size_t)NN * NC);
  const int row0 = i0 + w * 48 + lk * 4;
  const int colb = n0 + lm;
#pragma unroll
  for (int mt = 0; mt < 3; ++mt)
#pragma unroll
    for (int nt = 0; nt < 9; ++nt)
#pragma unroll
      for (int rr = 0; rr < 4; ++rr)
        o[(size_t)(row0 + mt * 16 + rr) * NC + colb + nt * 16] = acc[mt][nt][rr];
}

// ---------------- k3: combine across nks K-partials ----------------
__global__ __launch_bounds__(256) void k3_final(
    const float* __restrict__ out2, const float* __restrict__ e_src,
    const float* __restrict__ T, float* __restrict__ out, int nks)
{
  const int n = blockIdx.x, c = threadIdx.x;
  const int h = c >> 6, d = c & 63;
  float Se = 0.f, Sp = 0.f, E = 0.f, dg = 0.f;
  for (int s = 0; s < nks; ++s) {
    const float* ra = out2 + (size_t)s * ((size_t)NN * NC) + (size_t)n * NC;
    Se += ra[h * 128 + d];
    Sp += ra[h * 128 + 64 + d];
    E  += ra[512 + h];
    dg += ra[516];
  }
  float e = e_src[h * NN + n];
  float D = e * E + ((float)NN - dg);
  out[(size_t)n * 256 + c] = (e * Se + (T[c] - Sp)) / D;
}

extern "C" void kernel_launch(void* const* d_in, const int* in_sizes, int n_in,
                              void* d_out, int out_size, void* d_ws, size_t ws_size,
                              hipStream_t stream) {
  const float* x  = (const float*)d_in[0];
  const int*   adj= (const int*)d_in[1];
  const float* W  = (const float*)d_in[2];
  const float* Wb = (const float*)d_in[3];
  const float* Aw = (const float*)d_in[4];
  const float* Ab = (const float*)d_in[5];
  float* out = (float*)d_out;
  char* ws = (char*)d_ws;
  unsigned char* V8 = (unsigned char*)ws;                 // 3,538,944
  float* e_src = (float*)(ws + 3538944);                  // 98,304
  float* T     = (float*)(ws + 3637248);                  // 1,024
  float* Acat  = (float*)(ws + 3638272);                  // 3,072 (asv|adv|Wbc)
  unsigned short* Wt  = (unsigned short*)(ws + 3641344);  // 131,072
  unsigned short* xbf = (unsigned short*)(ws + 3772416);  // 3,145,728
  unsigned char* A8   = (unsigned char*)(ws + 6918144);   // 37,748,736
  float* out2  = (float*)(ws + 44666880);                 // nks x 14,155,776

  const size_t slab = (size_t)NN * NC * 4;
  const size_t base = 44666880;
  int nks = 2;
  if (ws_size >= base + 6 * slab)      nks = 6;
  else if (ws_size >= base + 4 * slab) nks = 4;

  hipLaunchKernelGGL(p0, dim3(4649), dim3(256), 0, stream,
                     adj, x, W, Aw, Wb, A8, xbf, Wt, Acat, T);
  hipLaunchKernelGGL(k1_mfma, dim3(192), dim3(256), 0, stream,
                     xbf, Wt, Acat, Ab, V8, e_src, T);
  hipLaunchKernelGGL(k2_gemm, dim3(128 * nks), dim3(256), 0, stream, A8, V8, out2, nks);
  hipLaunchKernelGGL(k3_final, dim3(NN), dim3(256), 0, stream, out2, e_src, T, out, nks);
}

// Round 10
// 318.979 us; speedup vs baseline: 1.4047x; 1.4047x over previous
//
#include <hip/hip_runtime.h>
#include <stdint.h>

#define NN 6144        // nodes
#define NC 576         // padded V columns (517 used)

typedef float f32x4 __attribute__((ext_vector_type(4)));
typedef __bf16 bf16x8v __attribute__((ext_vector_type(8)));

__device__ __forceinline__ unsigned short f2bf(float f) {
  unsigned u = __float_as_uint(f);
  u += 0x7FFFu + ((u >> 16) & 1u);   // RNE
  return (unsigned short)(u >> 16);
}

// f32 -> OCP e4m3fn, RNE, clamp to +-448
__device__ __forceinline__ unsigned char f2e4m3(float f) {
  unsigned u = __float_as_uint(f);
  unsigned sgn = (u >> 24) & 0x80u;
  unsigned au = u & 0x7FFFFFFFu;
  if (au >= 0x43E00000u) return (unsigned char)(sgn | 0x7E);
  if (au < 0x3C800000u) {
    int q = (int)rintf(__uint_as_float(au) * 512.0f);
    return (unsigned char)(sgn | (q >= 8 ? 0x08 : q));
  }
  unsigned r = au + 0x7FFFFu + ((au >> 20) & 1u);
  int e = (int)(r >> 23) - 127;
  unsigned m = (r >> 20) & 7u;
  return (unsigned char)(sgn | ((unsigned)(e + 7) << 3) | m);
}

__device__ __forceinline__ unsigned short pack2(float a, float b) {
  return (unsigned short)f2e4m3(a) | ((unsigned short)f2e4m3(b) << 8);
}

__device__ __forceinline__ void async_load16(const void* g, void* l) {
  __builtin_amdgcn_global_load_lds(
      (__attribute__((address_space(1))) void*)(uintptr_t)g,
      (__attribute__((address_space(3))) void*)(uint32_t)(uintptr_t)l,
      16, 0, 0);
}

// ---------------- p0: all prep ----------------
// blocks 0..7: W -> wsw (MFMA-fragment-swizzled bf16); 8: Acat+Wbc+T;
// 9..32: x -> xsw (fragment-swizzled bf16); 33..4640: adj -> fp8.
// Fragment order: entry e = ((tile*8 + kc)*64 + lane); lane lm=e&15 is row/col,
// lk=(e>>4)&3 picks k-sub-chunk: element [tile*16+lm][kc*32+lk*8+j], j=0..7.
__global__ __launch_bounds__(256) void p0(
    const int* __restrict__ adj, const float* __restrict__ x,
    const float* __restrict__ W, const float* __restrict__ Aw,
    const float* __restrict__ Wb,
    unsigned char* __restrict__ A8, unsigned short* __restrict__ xsw,
    unsigned short* __restrict__ wsw, float* __restrict__ Acat,
    float* __restrict__ T)
{
  const int bid = blockIdx.x, t = threadIdx.x;
  if (bid < 8) {           // wsw: 8192 entries (16 col-tiles x 8 kc x 64 lanes)
#pragma unroll
    for (int i = 0; i < 4; ++i) {
      const int e = bid * 256 + t + i * 2048;
      const int l = e & 63, kc = (e >> 6) & 7, ct = e >> 9;
      const int c = ct * 16 + (l & 15);
      const int h = c >> 6, d = c & 63;
      const int ks = kc * 32 + (l >> 4) * 8;
      const float* src = W + h * 16384 + ks * 64 + d;
      unsigned uu[4];
#pragma unroll
      for (int j = 0; j < 4; ++j)
        uu[j] = (unsigned)f2bf(src[(2*j) * 64]) | ((unsigned)f2bf(src[(2*j+1) * 64]) << 16);
      *(uint4*)(wsw + (size_t)e * 8) = (uint4){uu[0], uu[1], uu[2], uu[3]};
    }
    return;
  }
  if (bid == 8) {          // Acat[asv|adv|Wbc], T zero
    T[t] = 0.f;
    const int h = t >> 6, d = t & 63;
    Acat[t]       = Aw[h * 128 + d];
    Acat[256 + t] = Aw[h * 128 + 64 + d];
    Acat[512 + t] = Wb[t];
    return;
  }
  if (bid < 33) {          // xsw: 196,608 entries (384 m-tiles x 8 kc x 64 lanes)
    const int tid = (bid - 9) * 256 + t;
#pragma unroll 4
    for (int i = 0; i < 32; ++i) {
      const int e = tid + i * 6144;
      const int l = e & 63, kc = (e >> 6) & 7, mt = e >> 9;
      const int node = mt * 16 + (l & 15);
      const int ks = kc * 32 + (l >> 4) * 8;
      const float4* xp = (const float4*)(x + (size_t)node * 256 + ks);
      float4 v0 = xp[0], v1 = xp[1];
      uint4 o;
      o.x = (unsigned)f2bf(v0.x) | ((unsigned)f2bf(v0.y) << 16);
      o.y = (unsigned)f2bf(v0.z) | ((unsigned)f2bf(v0.w) << 16);
      o.z = (unsigned)f2bf(v1.x) | ((unsigned)f2bf(v1.y) << 16);
      o.w = (unsigned)f2bf(v1.z) | ((unsigned)f2bf(v1.w) << 16);
      *(uint4*)(xsw + (size_t)e * 8) = o;
    }
    return;
  }
  // adj pack: 4608 blocks x 256 thr x 8 int4-groups, lane-contiguous, 8 indep loads
  const int pb = bid - 33;
  const int4* a4 = (const int4*)adj;
  unsigned* o1 = (unsigned*)A8;
  const int g0 = pb * 2048 + t;
  int4 q[8];
#pragma unroll
  for (int j = 0; j < 8; ++j) q[j] = a4[g0 + j * 256];
#pragma unroll
  for (int j = 0; j < 8; ++j)
    o1[g0 + j * 256] = (unsigned)q[j].x * 0x38u | (unsigned)q[j].y * 0x3800u |
                       (unsigned)q[j].z * 0x380000u | (unsigned)q[j].w * 0x38000000u;
}

// ---------------- k1_mfma v2: h = x@W + Wb; epilogue e_src, e', V8, T ----------------
// 192 blocks x 4 waves; wave = 16-node m-tile x 128-col half (2 heads).
// All fragment loads contiguous 1KB/wave (pre-swizzled); V8 via per-wave LDS transpose
// (16B/lane stores); T via LDS reduction + 1 atomic/col/block.
__global__ __launch_bounds__(256) void k1_mfma(
    const unsigned short* __restrict__ xsw, const unsigned short* __restrict__ wsw,
    const float* __restrict__ Acat, const float* __restrict__ Ab,
    unsigned char* __restrict__ V8, float* __restrict__ e_src, float* __restrict__ T)
{
  __shared__ unsigned char lv[4][4096];   // per-wave: 256 local cols x 16 nodes
  __shared__ float lt[256];
  const int t = threadIdx.x;
  const int w = t >> 6, l = t & 63;
  const int v = blockIdx.x * 4 + w;
  const int mt = v >> 1, nh = v & 1;
  const int i0 = mt * 16, c0 = nh * 128;
  const int lm = l & 15, lk = l >> 4;

  lt[t] = 0.f;
  __syncthreads();

  f32x4 acc[8];
#pragma unroll
  for (int nt = 0; nt < 8; ++nt) acc[nt] = (f32x4){0.f, 0.f, 0.f, 0.f};

  const unsigned short* ap = xsw + ((size_t)mt * 512 + l) * 8;
  const unsigned short* bp = wsw + ((size_t)nh * 4096 + l) * 8;

#pragma unroll
  for (int kc = 0; kc < 8; ++kc) {
    bf16x8v a = *(const bf16x8v*)(ap + (size_t)kc * 512);
#pragma unroll
    for (int nt = 0; nt < 8; ++nt) {
      bf16x8v b = *(const bf16x8v*)(bp + ((size_t)nt * 512 + kc * 64) * 8);
      acc[nt] = __builtin_amdgcn_mfma_f32_16x16x32_bf16(a, b, acc[nt], 0, 0, 0);
    }
  }

  // C/D: col = c0 + nt*16 + lm, node = i0 + lk*4 + rr.  Add Wb bias.
  float asv[8], adv[8];
#pragma unroll
  for (int nt = 0; nt < 8; ++nt) {
    const int cc = c0 + nt * 16 + lm;
    const float wb = Acat[512 + cc];
#pragma unroll
    for (int rr = 0; rr < 4; ++rr) acc[nt][rr] += wb;
    asv[nt] = Acat[cc];
    adv[nt] = Acat[256 + cc];
  }

  // T partials into LDS (4-way same-address LDS atomics per nt — cheap)
#pragma unroll
  for (int nt = 0; nt < 8; ++nt)
    atomicAdd(&lt[c0 + nt * 16 + lm], acc[nt][0] + acc[nt][1] + acc[nt][2] + acc[nt][3]);

  // attention dots + 16-lane reductions
  float ss[2][4], sd[2][4];
#pragma unroll
  for (int hl = 0; hl < 2; ++hl)
#pragma unroll
    for (int rr = 0; rr < 4; ++rr) {
      float s1 = 0.f, s2 = 0.f;
#pragma unroll
      for (int j = 0; j < 4; ++j) {
        s1 += acc[hl * 4 + j][rr] * asv[hl * 4 + j];
        s2 += acc[hl * 4 + j][rr] * adv[hl * 4 + j];
      }
      ss[hl][rr] = s1; sd[hl][rr] = s2;
    }
#pragma unroll
  for (int off = 1; off < 16; off <<= 1)
#pragma unroll
    for (int hl = 0; hl < 2; ++hl)
#pragma unroll
      for (int rr = 0; rr < 4; ++rr) {
        ss[hl][rr] += __shfl_xor(ss[hl][rr], off);
        sd[hl][rr] += __shfl_xor(sd[hl][rr], off);
      }

  float ed[2][4];
#pragma unroll
  for (int hl = 0; hl < 2; ++hl)
#pragma unroll
    for (int rr = 0; rr < 4; ++rr) ed[hl][rr] = expf(sd[hl][rr]);

  if (lm == 0) {
#pragma unroll
    for (int hl = 0; hl < 2; ++hl) {
      const int hh = nh * 2 + hl;
      const float ab = Ab[hh];
#pragma unroll
      for (int rr = 0; rr < 4; ++rr)
        e_src[(size_t)hh * NN + i0 + lk * 4 + rr] = expf(ss[hl][rr] + ab);
    }
  }

  // V8 fragments -> per-wave LDS (local col lc: global col = nh*256 + lc)
  unsigned char* mylv = lv[w];
#pragma unroll
  for (int nt = 0; nt < 8; ++nt) {
    const int hl = nt >> 2;
    const int d = (nt & 3) * 16 + lm;
    const int lcE = hl * 128 + d;       // e'.h section
    const int lcP = lcE + 64;           // plain h section
    *(unsigned short*)(mylv + lcE * 16 + lk * 4)     = pack2(ed[hl][0] * acc[nt][0], ed[hl][1] * acc[nt][1]);
    *(unsigned short*)(mylv + lcE * 16 + lk * 4 + 2) = pack2(ed[hl][2] * acc[nt][2], ed[hl][3] * acc[nt][3]);
    *(unsigned short*)(mylv + lcP * 16 + lk * 4)     = pack2(acc[nt][0], acc[nt][1]);
    *(unsigned short*)(mylv + lcP * 16 + lk * 4 + 2) = pack2(acc[nt][2], acc[nt][3]);
  }
  // wave-local readback: 16B/lane contiguous stores to V8
#pragma unroll
  for (int j = 0; j < 4; ++j) {
    const int lc = j * 64 + l;
    uint4 val = *(const uint4*)(mylv + lc * 16);
    *(uint4*)(V8 + (size_t)(nh * 256 + lc) * NN + i0) = val;
  }
  if (lm == 0) {  // e' cols 512+hh, ones col 516
#pragma unroll
    for (int hl = 0; hl < 2; ++hl) {
      const int hh = nh * 2 + hl;
      unsigned char* pq = V8 + (size_t)(512 + hh) * NN + i0 + lk * 4;
      *(unsigned short*)pq       = pack2(ed[hl][0], ed[hl][1]);
      *(unsigned short*)(pq + 2) = pack2(ed[hl][2], ed[hl][3]);
    }
    if (nh == 0)
      *(unsigned*)(V8 + (size_t)516 * NN + i0 + lk * 4) = 0x38383838u;
  }

  __syncthreads();
  atomicAdd(&T[t], lt[t]);   // one global atomic per col per block
}

// ---------------- k2: out2[ks] = A8 @ V8 (R6-verified, unchanged) ----------------
__global__ __launch_bounds__(256, 3) void k2_gemm(
    const unsigned char* __restrict__ A8, const unsigned char* __restrict__ V8,
    float* __restrict__ out2, int nks)
{
  __shared__ unsigned char lB[144 * 64];
  const int t   = threadIdx.x;
  const int bid = blockIdx.x;
  const int cb  = bid & 3;
  const int rb  = (bid >> 2) & 31;
  const int ks  = bid >> 7;
  const int krange = NN / nks;
  const int i0 = rb * 192, n0 = cb * 144, k0 = ks * krange;
  const int w = t >> 6, l = t & 63;
  const int lm = l & 15, lk = l >> 4;

  f32x4 acc[3][9];
#pragma unroll
  for (int mt = 0; mt < 3; ++mt)
#pragma unroll
    for (int nt = 0; nt < 9; ++nt) acc[mt][nt] = (f32x4){0.f, 0.f, 0.f, 0.f};

  const unsigned char* gA0 = A8 + (size_t)(i0 + w * 48 + lm) * NN + k0 + lk * 16;

  const int iters = krange / 64;
  for (int it = 0; it < iters; ++it) {
    const int kb = k0 + it * 64;
    {
      const unsigned char* gB = V8 + (size_t)n0 * NN + kb;
#pragma unroll
      for (int u = 0; u < 2; ++u) {
        const int gi = u * 256 + t;
        const int col = gi >> 2;
        const int g = (gi & 3) ^ ((col ^ (col >> 2)) & 3);
        async_load16(gB + (size_t)col * NN + g * 16,
                     (char*)lB + (size_t)(u * 256 + (t & ~63)) * 16);
      }
      if (t < 64) {
        const int gi = 512 + t;
        const int col = gi >> 2;
        const int g = (gi & 3) ^ ((col ^ (col >> 2)) & 3);
        async_load16(gB + (size_t)col * NN + g * 16, (char*)lB + (size_t)512 * 16);
      }
    }
    longlong2 afr[3];
    const unsigned char* gA = gA0 + it * 64;
#pragma unroll
    for (int mt = 0; mt < 3; ++mt)
      afr[mt] = *(const longlong2*)(gA + (size_t)mt * 16 * NN);
    __syncthreads();
#pragma unroll
    for (int ks2 = 0; ks2 < 2; ++ks2) {
#pragma unroll
      for (int nt = 0; nt < 9; ++nt) {
        const int cc = nt * 16 + lm;
        const int sc = (cc ^ (cc >> 2)) & 3;
        long b = *(const long*)(lB + cc * 64 + ((lk ^ sc) * 16) + ks2 * 8);
#pragma unroll
        for (int mt = 0; mt < 3; ++mt)
          acc[mt][nt] = __builtin_amdgcn_mfma_f32_16x16x32_fp8_fp8(
              ks2 ? afr[mt].y : afr[mt].x, b, acc[mt][nt], 0, 0, 0);
      }
    }
    __syncthreads();
  }

  float* o = out2 + (size_t)ks * ((size_t)NN * NC);
  const int row0 = i0 + w * 48 + lk * 4;
  const int colb = n0 + lm;
#pragma unroll
  for (int mt = 0; mt < 3; ++mt)
#pragma unroll
    for (int nt = 0; nt < 9; ++nt)
#pragma unroll
      for (int rr = 0; rr < 4; ++rr)
        o[(size_t)(row0 + mt * 16 + rr) * NC + colb + nt * 16] = acc[mt][nt][rr];
}

// ---------------- k3: combine across nks K-partials ----------------
__global__ __launch_bounds__(256) void k3_final(
    const float* __restrict__ out2, const float* __restrict__ e_src,
    const float* __restrict__ T, float* __restrict__ out, int nks)
{
  const int n = blockIdx.x, c = threadIdx.x;
  const int h = c >> 6, d = c & 63;
  float Se = 0.f, Sp = 0.f, E = 0.f, dg = 0.f;
  for (int s = 0; s < nks; ++s) {
    const float* ra = out2 + (size_t)s * ((size_t)NN * NC) + (size_t)n * NC;
    Se += ra[h * 128 + d];
    Sp += ra[h * 128 + 64 + d];
    E  += ra[512 + h];
    dg += ra[516];
  }
  float e = e_src[h * NN + n];
  float D = e * E + ((float)NN - dg);
  out[(size_t)n * 256 + c] = (e * Se + (T[c] - Sp)) / D;
}

extern "C" void kernel_launch(void* const* d_in, const int* in_sizes, int n_in,
                              void* d_out, int out_size, void* d_ws, size_t ws_size,
                              hipStream_t stream) {
  const float* x  = (const float*)d_in[0];
  const int*   adj= (const int*)d_in[1];
  const float* W  = (const float*)d_in[2];
  const float* Wb = (const float*)d_in[3];
  const float* Aw = (const float*)d_in[4];
  const float* Ab = (const float*)d_in[5];
  float* out = (float*)d_out;
  char* ws = (char*)d_ws;
  unsigned char* V8 = (unsigned char*)ws;                 // 3,538,944
  float* e_src = (float*)(ws + 3538944);                  // 98,304
  float* T     = (float*)(ws + 3637248);                  // 1,024
  float* Acat  = (float*)(ws + 3638272);                  // 3,072 (asv|adv|Wbc)
  unsigned short* wsw = (unsigned short*)(ws + 3641344);  // 131,072
  unsigned short* xsw = (unsigned short*)(ws + 3772416);  // 3,145,728
  unsigned char* A8   = (unsigned char*)(ws + 6918144);   // 37,748,736
  float* out2  = (float*)(ws + 44666880);                 // nks x 14,155,776

  const size_t slab = (size_t)NN * NC * 4;
  const size_t base = 44666880;
  int nks = 2;
  if (ws_size >= base + 6 * slab)      nks = 6;
  else if (ws_size >= base + 4 * slab) nks = 4;

  hipLaunchKernelGGL(p0, dim3(4641), dim3(256), 0, stream,
                     adj, x, W, Aw, Wb, A8, xsw, wsw, Acat, T);
  hipLaunchKernelGGL(k1_mfma, dim3(192), dim3(256), 0, stream,
                     xsw, wsw, Acat, Ab, V8, e_src, T);
  hipLaunchKernelGGL(k2_gemm, dim3(128 * nks), dim3(256), 0, stream, A8, V8, out2, nks);
  hipLaunchKernelGGL(k3_final, dim3(NN), dim3(256), 0, stream, out2, e_src, T, out, nks);
}